// Round 14
// baseline (57.492 us; speedup 1.0000x reference)
//
#include <hip/hip_runtime.h>
#include <cstdint>
#include <cstddef>

// Problem constants (from reference)
#define EMB 256
#define NH 8
#define HD 32
#define NG 8
#define TMAX 24

// attention tiling
#define LMAX 384                 // max nodes/graph
#define LB 384                   // bias matrix row stride (f32)
#define TPB 6                    // 64-row query tiles per group = LMAX/64
#define VRU 200                  // u32 stride of a Vt row (800B -> uniform bank spread)
#define FM 8.0f                  // fixed softmax shift (scores bounded ~|10|)

typedef short s16x8 __attribute__((ext_vector_type(8)));
typedef float f32x4 __attribute__((ext_vector_type(4)));

__device__ __forceinline__ unsigned short f2b(float f) {
    unsigned u = __float_as_uint(f);
    return (unsigned short)((u + 0x7FFFu + ((u >> 16) & 1u)) >> 16);   // RNE
}
__device__ __forceinline__ float b2f(unsigned short h) {
    return __uint_as_float((unsigned)h << 16);
}
__device__ __forceinline__ unsigned long long pack4(unsigned short a, unsigned short b,
                                                    unsigned short c, unsigned short d) {
    return (unsigned long long)a | ((unsigned long long)b << 16) |
           ((unsigned long long)c << 32) | ((unsigned long long)d << 48);
}

// A/B-frag layout: element (row, k) of a [M][256] bf16 matrix lives at short index
//   ((row>>4)*8 + (k>>5))*512 + (((k>>3)&3)*16 + (row&15))*8 + (k&7)
// so a wave (lane = lq*16+lr) reads a 16x(32k) fragment as ONE contiguous 1KB load.
__device__ __forceinline__ size_t afrag_idx(int row, int k) {
    return ((size_t)((row >> 4) * 8 + (k >> 5)) << 9) +
           ((((k >> 3) & 3) * 16 + (row & 15)) << 3) + (k & 7);
}

// ---------------------------------------------------------------------------
// K1: fused prep. Segments by blockIdx.x:
//   [0, zb)           zero Bias (float4)
//   [zb, zb+cvtb)     x -> split bf16 (A-frag order)
//   [.., +cvtb)       gather temporal emb -> split bf16 (A-frag order)
//   [.., +448)        transpose+convert 7 weight matrices (B-frag order)
//   last block        gstart lower_bounds
struct PrepArgs {
    float4* Bias4; int bias4;
    const float* x; unsigned short* xh; unsigned short* xl;
    const float* temb; const int* ti; unsigned short* eh; unsigned short* el;
    const float* W[7]; unsigned short* whb; unsigned short* wlb;
    const int* batch; int* gstart; int n;
    int zb, cvtb;
};

__global__ __launch_bounds__(256) void k_prep(PrepArgs pa) {
    __shared__ float tile[32][33];
    int b = blockIdx.x;
    const int t = threadIdx.x;

    if (b < pa.zb) {                               // ---- zero Bias ----
        int i = b * 256 + t;
        if (i < pa.bias4) pa.Bias4[i] = make_float4(0.f, 0.f, 0.f, 0.f);
        return;
    }
    b -= pa.zb;
    if (b < pa.cvtb) {                             // ---- x -> split bf16, A-frag ----
        int i = b * 256 + t;
        if (i < pa.n * (EMB / 4)) {
            int row = i >> 6, k4 = (i & 63) * 4;
            float4 v = ((const float4*)pa.x)[i];
            unsigned short h0 = f2b(v.x), h1 = f2b(v.y), h2 = f2b(v.z), h3 = f2b(v.w);
            size_t o = afrag_idx(row, k4) >> 2;    // 8B-aligned (k4%4==0)
            ((unsigned long long*)pa.xh)[o] = pack4(h0, h1, h2, h3);
            ((unsigned long long*)pa.xl)[o] = pack4(f2b(v.x - b2f(h0)), f2b(v.y - b2f(h1)),
                                                    f2b(v.z - b2f(h2)), f2b(v.w - b2f(h3)));
        }
        return;
    }
    b -= pa.cvtb;
    if (b < pa.cvtb) {                             // ---- gather emb -> split bf16, A-frag ----
        int idx = b * 256 + t;
        if (idx < pa.n * (EMB / 4)) {
            int row = idx >> 6, k4 = (idx & 63) * 4;
            int tt = pa.ti[row];
            tt = tt < 0 ? 0 : (tt > TMAX - 1 ? TMAX - 1 : tt);
            float4 v = ((const float4*)pa.temb)[tt * (EMB / 4) + (idx & 63)];
            unsigned short h0 = f2b(v.x), h1 = f2b(v.y), h2 = f2b(v.z), h3 = f2b(v.w);
            size_t o = afrag_idx(row, k4) >> 2;
            ((unsigned long long*)pa.eh)[o] = pack4(h0, h1, h2, h3);
            ((unsigned long long*)pa.el)[o] = pack4(f2b(v.x - b2f(h0)), f2b(v.y - b2f(h1)),
                                                    f2b(v.z - b2f(h2)), f2b(v.w - b2f(h3)));
        }
        return;
    }
    b -= pa.cvtb;
    if (b < 448) {                                 // ---- wtrans: W[k][n] -> B-frag order ----
        const int z = b >> 6, rem = b & 63;
        const int k0 = (rem >> 3) << 5, n0 = (rem & 7) << 5;
        const float* W = pa.W[z];
        unsigned short* Wh = pa.whb + (size_t)z * 65536;
        unsigned short* Wl = pa.wlb + (size_t)z * 65536;
        {
            int rr = t >> 3, c4 = (t & 7) * 4;
            float4 v = *(const float4*)(W + (size_t)(k0 + rr) * 256 + n0 + c4);
            tile[rr][c4 + 0] = v.x; tile[rr][c4 + 1] = v.y;
            tile[rr][c4 + 2] = v.z; tile[rr][c4 + 3] = v.w;
        }
        __syncthreads();
        {
            int nn = n0 + (t >> 3), k4 = (t & 7) * 4;   // element (n=nn, k=k0+k4..+3)
            float v0 = tile[k4 + 0][t >> 3], v1 = tile[k4 + 1][t >> 3];
            float v2 = tile[k4 + 2][t >> 3], v3 = tile[k4 + 3][t >> 3];
            unsigned short h0 = f2b(v0), h1 = f2b(v1), h2 = f2b(v2), h3 = f2b(v3);
            size_t o = afrag_idx(nn, k0 + k4) >> 2;     // same formula, n plays "row"
            ((unsigned long long*)Wh)[o] = pack4(h0, h1, h2, h3);
            ((unsigned long long*)Wl)[o] = pack4(f2b(v0 - b2f(h0)), f2b(v1 - b2f(h1)),
                                                 f2b(v2 - b2f(h2)), f2b(v3 - b2f(h3)));
        }
        return;
    }
    // ---- gstart ----
    if (t <= NG) {
        int lo = 0, hi = pa.n;
        while (lo < hi) {
            int mid = (lo + hi) >> 1;
            if (pa.batch[mid] < t) lo = mid + 1; else hi = mid;
        }
        pa.gstart[t] = lo;
    }
}

// ---------------------------------------------------------------------------
// K2: six split-bf16 MFMA projections (z<6, frag-order operands, head-major out)
//     + edge-bias scatter (z==6).
// Q/TQ (Clo != null): full 3-pass split. K/V/TK/TV: 2-pass (drop al*bh).
struct GB {
    const unsigned short* Ah[6];
    const unsigned short* Al[6];
    const float* bias[6];
    unsigned short* Chi[6];   // head-major [NH][M][HD]
    unsigned short* Clo[6];   // non-null -> also store residual lo
    float cscale[6];
};

__global__ __launch_bounds__(256) void k_gemm_split(GB gb,
        const unsigned short* __restrict__ whb, const unsigned short* __restrict__ wlb, int M,
        const int* __restrict__ ei, const float* __restrict__ eattr,
        const float* __restrict__ We, const float* __restrict__ be,
        const int* __restrict__ batch, const int* __restrict__ gstart,
        float* __restrict__ Bias, int E) {
    const int z = blockIdx.z;
    const int t = threadIdx.x;

    if (z == 6) {            // ---- edge bias scatter into dense Bias ----
        const int stride = gridDim.x * gridDim.y * 256;
        for (int e = (blockIdx.y * gridDim.x + blockIdx.x) * 256 + t; e < E; e += stride) {
            int src = ei[e], dst = ei[E + e];
            if (src < 0 || src >= M || dst < 0 || dst >= M) continue;
            int bs = batch[src];
            if (bs != batch[dst]) continue;
            float4 a = *(const float4*)(eattr + (size_t)e * 4);
            int col = dst - gstart[bs];
#pragma unroll
            for (int h = 0; h < NH; h++) {
                float v = a.x * We[0 * NH + h] + a.y * We[1 * NH + h] +
                          a.z * We[2 * NH + h] + a.w * We[3 * NH + h] + be[h];
                atomicAdd(Bias + ((size_t)h * M + src) * LB + col, v);
            }
        }
        return;
    }

    const unsigned short* Ah = gb.Ah[z];
    const unsigned short* Al = gb.Al[z];
    const unsigned short* Wh = whb + (size_t)z * 65536;
    const unsigned short* Wl = wlb + (size_t)z * 65536;
    const float* bias = gb.bias[z];
    unsigned short* Chi = gb.Chi[z];
    unsigned short* Clo = gb.Clo[z];
    const float cs = gb.cscale[z];
    const bool fs = (Clo != nullptr);         // full-split arithmetic for Q/TQ only

    const int lane = t & 63, wv = t >> 6, lr = lane & 15, lq = lane >> 4;
    const int bm = blockIdx.x * 64 + (wv >> 1) * 32;
    const int bn = blockIdx.y * 64 + (wv & 1) * 32;
    const int mg0 = bm >> 4, ng0 = bn >> 4;     // fragment group bases (M%64==0)

    f32x4 acc[2][2] = {};
#pragma unroll
    for (int kc = 0; kc < 8; kc++) {
        s16x8 ah[2], al[2], bh[2], bl[2];
#pragma unroll
        for (int mi = 0; mi < 2; mi++) {
            size_t o = ((size_t)((mg0 + mi) * 8 + kc) << 9) + lane * 8;   // contiguous 1KB/wave
            ah[mi] = *(const s16x8*)(Ah + o);
            if (fs) al[mi] = *(const s16x8*)(Al + o);
        }
#pragma unroll
        for (int ni = 0; ni < 2; ni++) {
            size_t o = ((size_t)((ng0 + ni) * 8 + kc) << 9) + lane * 8;
            bh[ni] = *(const s16x8*)(Wh + o);
            bl[ni] = *(const s16x8*)(Wl + o);
        }
#pragma unroll
        for (int mi = 0; mi < 2; mi++)
#pragma unroll
            for (int ni = 0; ni < 2; ni++) {
                if (fs)
                    acc[mi][ni] = __builtin_amdgcn_mfma_f32_16x16x32_bf16(al[mi], bh[ni], acc[mi][ni], 0, 0, 0);
                acc[mi][ni] = __builtin_amdgcn_mfma_f32_16x16x32_bf16(ah[mi], bl[ni], acc[mi][ni], 0, 0, 0);
                acc[mi][ni] = __builtin_amdgcn_mfma_f32_16x16x32_bf16(ah[mi], bh[ni], acc[mi][ni], 0, 0, 0);
            }
    }
#pragma unroll
    for (int ni = 0; ni < 2; ni++) {
        const int col = bn + ni * 16 + lr;        // bn%32==0 -> head uniform per ni
        const int hh = col >> 5, dd = col & 31;
        float bv = bias[col];
#pragma unroll
        for (int mi = 0; mi < 2; mi++) {
#pragma unroll
            for (int r = 0; r < 4; r++) {
                int crow = bm + mi * 16 + 4 * lq + r;
                if (crow < M) {
                    float val = (acc[mi][ni][r] + bv) * cs;
                    unsigned short h = f2b(val);
                    size_t o = ((size_t)hh * M + crow) * HD + dd;
                    Chi[o] = h;
                    if (fs) Clo[o] = f2b(val - b2f(h));
                }
            }
        }
    }
}

// ---------------------------------------------------------------------------
// K3: flash MFMA attention, PARALLEL-tz. Block = 8 waves (512): waves 0-3 do
// spatial (tz=0), waves 4-7 temporal (tz=1), same 64 q-rows. Both V^T buffers
// staged up front (1 barrier). Temporal waves deposit normalized output in LDS;
// spatial waves add (same order as r13: s*iv_s + t*iv_t -> bit-identical) and
// write combined as split-bf16 in A-frag order.
__global__ __launch_bounds__(512) void k_attn7(
    const unsigned short* __restrict__ Qh, const unsigned short* __restrict__ Ql,
    const unsigned short* __restrict__ K, const unsigned short* __restrict__ V,
    const unsigned short* __restrict__ TQh, const unsigned short* __restrict__ TQl,
    const unsigned short* __restrict__ TK, const unsigned short* __restrict__ TV,
    const int* __restrict__ gstart, const float* __restrict__ Bias,
    unsigned short* __restrict__ ch, unsigned short* __restrict__ cl, int n) {

    const int g  = blockIdx.x / TPB;
    const int tp = blockIdx.x % TPB;
    const int h  = blockIdx.y;
    const int gs = gstart[g], ge = gstart[g + 1];
    const int L  = ge - gs;
    const int q0b = tp * 64;
    if (q0b >= L) return;                    // uniform block-level exit (before barriers)
    const int NC = (L + 31) >> 5;            // 32-key chunks

    __shared__ __align__(16) unsigned int Vt[2][32 * VRU];       // 51.2 KB: V^T per tz
    __shared__ __align__(16) unsigned short Pb[8][16][40];       // 10.2 KB: per-wave P bounce
    __shared__ __align__(16) float Cmb[64][32];                  // 8 KB: temporal partials

    const int t = threadIdx.x;
    const int wv = t >> 6, lane = t & 63;
    const int lr = lane & 15, lq = lane >> 4;
    const int tz = wv >> 2, w4 = wv & 3;
    const size_t hb = (size_t)h * n;          // head-major base row

    // ---- cooperative staging of BOTH V^T buffers (all 8 waves) ----
    for (int z = 0; z < 2; z++) {
        const unsigned short* Vp = z ? TV : V;
        unsigned int* Vz = Vt[z];
        const int d0 = (t & 7) * 4;
        for (int jp = t >> 3; jp < NC * 16; jp += 64) {
            int j0 = jp * 2;
            unsigned short a0 = 0, a1 = 0, a2 = 0, a3 = 0, b0 = 0, b1 = 0, b2 = 0, b3 = 0;
            if (j0 < L) {
                const unsigned short* vp = Vp + (hb + gs + j0) * HD + d0;
                a0 = vp[0]; a1 = vp[1]; a2 = vp[2]; a3 = vp[3];
            }
            if (j0 + 1 < L) {
                const unsigned short* vp = Vp + (hb + gs + j0 + 1) * HD + d0;
                b0 = vp[0]; b1 = vp[1]; b2 = vp[2]; b3 = vp[3];
            }
            Vz[(d0 + 0) * VRU + jp] = (unsigned)a0 | ((unsigned)b0 << 16);
            Vz[(d0 + 1) * VRU + jp] = (unsigned)a1 | ((unsigned)b1 << 16);
            Vz[(d0 + 2) * VRU + jp] = (unsigned)a2 | ((unsigned)b2 << 16);
            Vz[(d0 + 3) * VRU + jp] = (unsigned)a3 | ((unsigned)b3 << 16);
        }
    }

    // ---- this wave's tz-specific pointers & Q fragments ----
    const unsigned short* Qph = tz ? TQh : Qh;
    const unsigned short* Qpl = tz ? TQl : Ql;
    const unsigned short* Kp  = tz ? TK  : K;
    const unsigned int*   Vz  = Vt[tz];
    const bool hasb = (tz == 0);

    const int q0w = q0b + w4 * 16;            // this wave's 16 rows (predicated)
    int gq = gs + q0w + lr;
    if (gq > ge - 1) gq = ge - 1;
    s16x8 qfh = *(const s16x8*)(Qph + (hb + gq) * HD + lq * 8);
    s16x8 qfl = *(const s16x8*)(Qpl + (hb + gq) * HD + lq * 8);
    __syncthreads();                          // Vt ready

    // ---- per-reg bias row bases (spatial waves only) ----
    const float* br0 = Bias; const float* br1 = Bias;
    const float* br2 = Bias; const float* br3 = Bias;
    if (hasb) {
        int r0 = gs + q0w + 4 * lq;
        int a0 = r0 + 0 < n ? r0 + 0 : n - 1;
        int a1 = r0 + 1 < n ? r0 + 1 : n - 1;
        int a2 = r0 + 2 < n ? r0 + 2 : n - 1;
        int a3 = r0 + 3 < n ? r0 + 3 : n - 1;
        br0 = Bias + (hb + a0) * LB;
        br1 = Bias + (hb + a1) * LB;
        br2 = Bias + (hb + a2) * LB;
        br3 = Bias + (hb + a3) * LB;
    }

    auto loadK = [&](int c, int half) -> s16x8 {
        int key = (2 * c + half) * 16 + lr;
        int krow = (key < L) ? (gs + key) : (ge - 1);
        return *(const s16x8*)(Kp + (hb + krow) * HD + lq * 8);
    };

    f32x4 acc0 = {0.f, 0.f, 0.f, 0.f};
    f32x4 acc1 = {0.f, 0.f, 0.f, 0.f};
    float ps0 = 0.f, ps1 = 0.f, ps2 = 0.f, ps3 = 0.f;

    s16x8 kfa = loadK(0, 0), kfb = loadK(0, 1);   // 1-deep prefetch
    for (int c = 0; c < NC; c++) {
        const int cn = (c + 1 < NC) ? c + 1 : c;
        s16x8 nka = loadK(cn, 0), nkb = loadK(cn, 1);

        float p[2][4];
#pragma unroll
        for (int half = 0; half < 2; half++) {
            const int key = (2 * c + half) * 16 + lr;
            s16x8 kf = half ? kfb : kfa;
            f32x4 d = {0.f, 0.f, 0.f, 0.f};
            d = __builtin_amdgcn_mfma_f32_16x16x32_bf16(qfl, kf, d, 0, 0, 0);
            d = __builtin_amdgcn_mfma_f32_16x16x32_bf16(qfh, kf, d, 0, 0, 0);
            float s0 = d[0], s1 = d[1], s2 = d[2], s3 = d[3];
            if (hasb) {
                s0 += br0[key]; s1 += br1[key]; s2 += br2[key]; s3 += br3[key];
            }
            const bool ok = key < L;
            s0 = ok ? s0 : -3.0e38f;
            s1 = ok ? s1 : -3.0e38f;
            s2 = ok ? s2 : -3.0e38f;
            s3 = ok ? s3 : -3.0e38f;
            p[half][0] = __expf(s0 - FM);
            p[half][1] = __expf(s1 - FM);
            p[half][2] = __expf(s2 - FM);
            p[half][3] = __expf(s3 - FM);
        }
        ps0 += p[0][0] + p[1][0];
        ps1 += p[0][1] + p[1][1];
        ps2 += p[0][2] + p[1][2];
        ps3 += p[0][3] + p[1][3];
        // transpose bounce: D-layout (row 4lq+r, col lr) -> A-layout (row lr, k 8lq+j)
#pragma unroll
        for (int half = 0; half < 2; half++) {
#pragma unroll
            for (int r = 0; r < 4; r++)
                Pb[wv][4 * lq + r][half * 16 + lr] = f2b(p[half][r]);
        }
        s16x8 pf  = *(const s16x8*)&Pb[wv][lr][8 * lq];
        s16x8 vf0 = *(const s16x8*)&Vz[(size_t)lr * VRU + c * 16 + lq * 4];
        s16x8 vf1 = *(const s16x8*)&Vz[(size_t)(16 + lr) * VRU + c * 16 + lq * 4];
        acc0 = __builtin_amdgcn_mfma_f32_16x16x32_bf16(pf, vf0, acc0, 0, 0, 0);
        acc1 = __builtin_amdgcn_mfma_f32_16x16x32_bf16(pf, vf1, acc1, 0, 0, 0);
        kfa = nka; kfb = nkb;
    }

    // ---- row-sums over the 16 lr lanes, normalize ----
#pragma unroll
    for (int m = 1; m < 16; m <<= 1) {
        ps0 += __shfl_xor(ps0, m, 16);
        ps1 += __shfl_xor(ps1, m, 16);
        ps2 += __shfl_xor(ps2, m, 16);
        ps3 += __shfl_xor(ps3, m, 16);
    }
    float iv0 = 1.0f / ps0, iv1 = 1.0f / ps1, iv2 = 1.0f / ps2, iv3 = 1.0f / ps3;
    float os0[4], os1[4];
    os0[0] = acc0[0] * iv0; os1[0] = acc1[0] * iv0;
    os0[1] = acc0[1] * iv1; os1[1] = acc1[1] * iv1;
    os0[2] = acc0[2] * iv2; os1[2] = acc1[2] * iv2;
    os0[3] = acc0[3] * iv3; os1[3] = acc1[3] * iv3;

    // ---- temporal waves deposit; spatial waves combine + store ----
    if (tz == 1) {
#pragma unroll
        for (int r = 0; r < 4; r++) {
            Cmb[w4 * 16 + 4 * lq + r][lr]      = os0[r];
            Cmb[w4 * 16 + 4 * lq + r][16 + lr] = os1[r];
        }
    }
    __syncthreads();
    if (tz == 0) {
        const int qb = q0w + 4 * lq;
#pragma unroll
        for (int r = 0; r < 4; r++) {
            if (qb + r < L) {
                const int grow = gs + qb + r;
                float v0 = os0[r] + Cmb[w4 * 16 + 4 * lq + r][lr];
                float v1 = os1[r] + Cmb[w4 * 16 + 4 * lq + r][16 + lr];
                unsigned short h0 = f2b(v0);
                unsigned short l0 = f2b(v0 - b2f(h0));
                unsigned short h1 = f2b(v1);
                unsigned short l1 = f2b(v1 - b2f(h1));
                size_t o0 = afrag_idx(grow, h * HD + lr);
                size_t o1 = afrag_idx(grow, h * HD + 16 + lr);
                ch[o0] = h0; cl[o0] = l0;
                ch[o1] = h1; cl[o1] = l1;
            }
        }
    }
}

// ---------------------------------------------------------------------------
// K4: split-bf16 MFMA output GEMM, frag-order A (from K3) and B (Wo).
// One wave per 16x32 C-tile: grid (M/16, 256/32) = 1024 blocks of 64 threads.
__global__ __launch_bounds__(64) void k_gemm_out(const unsigned short* __restrict__ Ah,
        const unsigned short* __restrict__ Al,
        const unsigned short* __restrict__ Wh, const unsigned short* __restrict__ Wl,
        const float* __restrict__ bias, float* __restrict__ C, int M) {
    const int lane = threadIdx.x;
    const int lr = lane & 15, lq = lane >> 4;
    const int bm = blockIdx.x * 16;
    const int bn = blockIdx.y * 32;
    const int mg = bm >> 4, ng0 = bn >> 4;

    f32x4 acc[2] = {};
#pragma unroll
    for (int kc = 0; kc < 8; kc++) {
        size_t oa = ((size_t)(mg * 8 + kc) << 9) + lane * 8;   // contiguous 1KB/wave
        s16x8 ah = *(const s16x8*)(Ah + oa);
        s16x8 al = *(const s16x8*)(Al + oa);
#pragma unroll
        for (int ni = 0; ni < 2; ni++) {
            size_t ob = ((size_t)((ng0 + ni) * 8 + kc) << 9) + lane * 8;
            s16x8 bh = *(const s16x8*)(Wh + ob);
            s16x8 bl = *(const s16x8*)(Wl + ob);
            acc[ni] = __builtin_amdgcn_mfma_f32_16x16x32_bf16(al, bh, acc[ni], 0, 0, 0);
            acc[ni] = __builtin_amdgcn_mfma_f32_16x16x32_bf16(ah, bl, acc[ni], 0, 0, 0);
            acc[ni] = __builtin_amdgcn_mfma_f32_16x16x32_bf16(ah, bh, acc[ni], 0, 0, 0);
        }
    }
#pragma unroll
    for (int ni = 0; ni < 2; ni++) {
        const int col = bn + ni * 16 + lr;
        float bv = bias[col];
#pragma unroll
        for (int r = 0; r < 4; r++) {
            const int crow = bm + 4 * lq + r;          // M%16==0 -> always in range
            C[(size_t)crow * 256 + col] = acc[ni][r] + bv;
        }
    }
}

// ---------------------------------------------------------------------------
extern "C" void kernel_launch(void* const* d_in, const int* in_sizes, int n_in,
                              void* d_out, int out_size, void* d_ws, size_t ws_size,
                              hipStream_t stream) {
    const float* x     = (const float*)d_in[0];
    const int*   ei    = (const int*)d_in[1];
    const float* eattr = (const float*)d_in[2];
    const int*   batch = (const int*)d_in[3];
    const int*   ti    = (const int*)d_in[4];
    const float* temb  = (const float*)d_in[5];
    const float* Wq = (const float*)d_in[6],  *bq = (const float*)d_in[7];
    const float* Wk = (const float*)d_in[8],  *bk = (const float*)d_in[9];
    const float* Wv = (const float*)d_in[10], *bv = (const float*)d_in[11];
    const float* Wo = (const float*)d_in[12], *bo = (const float*)d_in[13];
    const float* We = (const float*)d_in[14], *be = (const float*)d_in[15];
    const float* Wtq = (const float*)d_in[16], *btq = (const float*)d_in[17];
    const float* Wtk = (const float*)d_in[18], *btk = (const float*)d_in[19];
    const float* Wtv = (const float*)d_in[20], *btv = (const float*)d_in[21];

    const int n = in_sizes[0] / EMB;
    const int E = in_sizes[2] / 4;
    float* out = (float*)d_out;

    char* w = (char*)d_ws;
    auto alloc = [&](size_t bytes) -> void* {
        void* p = (void*)w;
        w += (bytes + 255) & ~(size_t)255;
        return p;
    };
    const size_t nb = (size_t)n * EMB * 2;   // one bf16 [n][256]-sized buffer
    unsigned short* xh   = (unsigned short*)alloc(nb);
    unsigned short* xl   = (unsigned short*)alloc(nb);
    unsigned short* eh   = (unsigned short*)alloc(nb);
    unsigned short* el   = (unsigned short*)alloc(nb);
    unsigned short* whb  = (unsigned short*)alloc((size_t)7 * 65536 * 2);
    unsigned short* wlb  = (unsigned short*)alloc((size_t)7 * 65536 * 2);
    unsigned short* Qhb  = (unsigned short*)alloc(nb);
    unsigned short* Qlb  = (unsigned short*)alloc(nb);
    unsigned short* Kb   = (unsigned short*)alloc(nb);
    unsigned short* Vb   = (unsigned short*)alloc(nb);
    unsigned short* TQhb = (unsigned short*)alloc(nb);
    unsigned short* TQlb = (unsigned short*)alloc(nb);
    unsigned short* TKb  = (unsigned short*)alloc(nb);
    unsigned short* TVb  = (unsigned short*)alloc(nb);
    float* Bias  = (float*)alloc((size_t)NH * n * LB * 4);      // 25 MB dense bias
    unsigned short* ch = (unsigned short*)alloc(nb);            // combined, frag order
    unsigned short* cl = (unsigned short*)alloc(nb);
    int* gstart  = (int*)alloc((NG + 1) * 4);

    // ---- K1: fused prep ----
    PrepArgs pa;
    pa.Bias4 = (float4*)Bias;
    pa.bias4 = NH * n * LB / 4;
    pa.x = x; pa.xh = xh; pa.xl = xl;
    pa.temb = temb; pa.ti = ti; pa.eh = eh; pa.el = el;
    pa.W[0] = Wq; pa.W[1] = Wk; pa.W[2] = Wv;
    pa.W[3] = Wtq; pa.W[4] = Wtk; pa.W[5] = Wtv; pa.W[6] = Wo;
    pa.whb = whb; pa.wlb = wlb;
    pa.batch = batch; pa.gstart = gstart; pa.n = n;
    pa.zb = (pa.bias4 + 255) / 256;
    pa.cvtb = (n * (EMB / 4) + 255) / 256;
    const int prep_blocks = pa.zb + 2 * pa.cvtb + 448 + 1;
    k_prep<<<dim3(prep_blocks), dim3(256), 0, stream>>>(pa);

    // ---- K2: projections (z<6, head-major out) + edge-bias scatter (z==6) ----
    const float scale = 0.17677669529663687f;
    GB gb;
    gb.Ah[0] = xh; gb.Al[0] = xl; gb.bias[0] = bq;  gb.Chi[0] = Qhb;  gb.Clo[0] = Qlb;  gb.cscale[0] = scale;
    gb.Ah[1] = xh; gb.Al[1] = xl; gb.bias[1] = bk;  gb.Chi[1] = Kb;   gb.Clo[1] = nullptr; gb.cscale[1] = 1.f;
    gb.Ah[2] = xh; gb.Al[2] = xl; gb.bias[2] = bv;  gb.Chi[2] = Vb;   gb.Clo[2] = nullptr; gb.cscale[2] = 1.f;
    gb.Ah[3] = eh; gb.Al[3] = el; gb.bias[3] = btq; gb.Chi[3] = TQhb; gb.Clo[3] = TQlb; gb.cscale[3] = scale;
    gb.Ah[4] = eh; gb.Al[4] = el; gb.bias[4] = btk; gb.Chi[4] = TKb;  gb.Clo[4] = nullptr; gb.cscale[4] = 1.f;
    gb.Ah[5] = eh; gb.Al[5] = el; gb.bias[5] = btv; gb.Chi[5] = TVb;  gb.Clo[5] = nullptr; gb.cscale[5] = 1.f;
    k_gemm_split<<<dim3((n + 63) / 64, EMB / 64, 7), dim3(256), 0, stream>>>(
        gb, whb, wlb, n, ei, eattr, We, be, batch, gstart, Bias, E);

    // ---- K3: parallel-tz flash MFMA attention -> combined (frag-order hi/lo) ----
    k_attn7<<<dim3(NG * TPB, NH), dim3(512), 0, stream>>>(Qhb, Qlb, Kb, Vb,
                                                          TQhb, TQlb, TKb, TVb,
                                                          gstart, Bias, ch, cl, n);
    // ---- K4: output projection (1024 one-wave blocks) ----
    k_gemm_out<<<dim3(n / 16, EMB / 32), dim3(64), 0, stream>>>(
        ch, cl, whb + (size_t)6 * 65536, wlb + (size_t)6 * 65536, bo, out, n);
}

// Round 15
// 56.842 us; speedup vs baseline: 1.0114x; 1.0114x over previous
//
#include <hip/hip_runtime.h>
#include <cstdint>
#include <cstddef>

// Problem constants (from reference)
#define EMB 256
#define NH 8
#define HD 32
#define NG 8
#define TMAX 24

// attention tiling
#define LMAX 384                 // max nodes/graph
#define LB 384                   // bias matrix row stride (u32 words, 2 heads/word)
#define TPB 6                    // 64-row query tiles per group = LMAX/64
#define VRU 200                  // u32 stride of a Vt row (800B -> uniform bank spread)
#define FM 8.0f                  // fixed softmax shift (scores bounded ~|10|)

typedef short s16x8 __attribute__((ext_vector_type(8)));
typedef float f32x4 __attribute__((ext_vector_type(4)));
typedef unsigned int u32x4 __attribute__((ext_vector_type(4)));

__device__ __forceinline__ unsigned short f2b(float f) {
    unsigned u = __float_as_uint(f);
    return (unsigned short)((u + 0x7FFFu + ((u >> 16) & 1u)) >> 16);   // RNE
}
__device__ __forceinline__ float b2f(unsigned short h) {
    return __uint_as_float((unsigned)h << 16);
}
__device__ __forceinline__ unsigned long long pack4(unsigned short a, unsigned short b,
                                                    unsigned short c, unsigned short d) {
    return (unsigned long long)a | ((unsigned long long)b << 16) |
           ((unsigned long long)c << 32) | ((unsigned long long)d << 48);
}

// A/B-frag layout: element (row, k) of a [M][256] bf16 matrix lives at short index
//   ((row>>4)*8 + (k>>5))*512 + (((k>>3)&3)*16 + (row&15))*8 + (k&7)
// so a wave (lane = lq*16+lr) reads a 16x(32k) fragment as ONE contiguous 1KB load.
__device__ __forceinline__ size_t afrag_idx(int row, int k) {
    return ((size_t)((row >> 4) * 8 + (k >> 5)) << 9) +
           ((((k >> 3) & 3) * 16 + (row & 15)) << 3) + (k & 7);
}

// ---------------------------------------------------------------------------
// K1: fused prep. Segments by blockIdx.x:
//   [0, zb)           zero packed Bias (uint4)
//   [zb, zb+cvtb)     x -> split bf16 (A-frag order)
//   [.., +cvtb)       gather temporal emb -> split bf16 (A-frag order)
//   [.., +448)        transpose+convert 7 weight matrices (B-frag order)
//   last block        gstart lower_bounds
struct PrepArgs {
    u32x4* Bias4; int bias4;
    const float* x; unsigned short* xh; unsigned short* xl;
    const float* temb; const int* ti; unsigned short* eh; unsigned short* el;
    const float* W[7]; unsigned short* whb; unsigned short* wlb;
    const int* batch; int* gstart; int n;
    int zb, cvtb;
};

__global__ __launch_bounds__(256) void k_prep(PrepArgs pa) {
    __shared__ float tile[32][33];
    int b = blockIdx.x;
    const int t = threadIdx.x;

    if (b < pa.zb) {                               // ---- zero packed Bias ----
        int i = b * 256 + t;
        if (i < pa.bias4) {
            u32x4 z = {0u, 0u, 0u, 0u};
            pa.Bias4[i] = z;
        }
        return;
    }
    b -= pa.zb;
    if (b < pa.cvtb) {                             // ---- x -> split bf16, A-frag ----
        int i = b * 256 + t;
        if (i < pa.n * (EMB / 4)) {
            int row = i >> 6, k4 = (i & 63) * 4;
            float4 v = ((const float4*)pa.x)[i];
            unsigned short h0 = f2b(v.x), h1 = f2b(v.y), h2 = f2b(v.z), h3 = f2b(v.w);
            size_t o = afrag_idx(row, k4) >> 2;    // 8B-aligned (k4%4==0)
            ((unsigned long long*)pa.xh)[o] = pack4(h0, h1, h2, h3);
            ((unsigned long long*)pa.xl)[o] = pack4(f2b(v.x - b2f(h0)), f2b(v.y - b2f(h1)),
                                                    f2b(v.z - b2f(h2)), f2b(v.w - b2f(h3)));
        }
        return;
    }
    b -= pa.cvtb;
    if (b < pa.cvtb) {                             // ---- gather emb -> split bf16, A-frag ----
        int idx = b * 256 + t;
        if (idx < pa.n * (EMB / 4)) {
            int row = idx >> 6, k4 = (idx & 63) * 4;
            int tt = pa.ti[row];
            tt = tt < 0 ? 0 : (tt > TMAX - 1 ? TMAX - 1 : tt);
            float4 v = ((const float4*)pa.temb)[tt * (EMB / 4) + (idx & 63)];
            unsigned short h0 = f2b(v.x), h1 = f2b(v.y), h2 = f2b(v.z), h3 = f2b(v.w);
            size_t o = afrag_idx(row, k4) >> 2;
            ((unsigned long long*)pa.eh)[o] = pack4(h0, h1, h2, h3);
            ((unsigned long long*)pa.el)[o] = pack4(f2b(v.x - b2f(h0)), f2b(v.y - b2f(h1)),
                                                    f2b(v.z - b2f(h2)), f2b(v.w - b2f(h3)));
        }
        return;
    }
    b -= pa.cvtb;
    if (b < 448) {                                 // ---- wtrans: W[k][n] -> B-frag order ----
        const int z = b >> 6, rem = b & 63;
        const int k0 = (rem >> 3) << 5, n0 = (rem & 7) << 5;
        const float* W = pa.W[z];
        unsigned short* Wh = pa.whb + (size_t)z * 65536;
        unsigned short* Wl = pa.wlb + (size_t)z * 65536;
        {
            int rr = t >> 3, c4 = (t & 7) * 4;
            float4 v = *(const float4*)(W + (size_t)(k0 + rr) * 256 + n0 + c4);
            tile[rr][c4 + 0] = v.x; tile[rr][c4 + 1] = v.y;
            tile[rr][c4 + 2] = v.z; tile[rr][c4 + 3] = v.w;
        }
        __syncthreads();
        {
            int nn = n0 + (t >> 3), k4 = (t & 7) * 4;   // element (n=nn, k=k0+k4..+3)
            float v0 = tile[k4 + 0][t >> 3], v1 = tile[k4 + 1][t >> 3];
            float v2 = tile[k4 + 2][t >> 3], v3 = tile[k4 + 3][t >> 3];
            unsigned short h0 = f2b(v0), h1 = f2b(v1), h2 = f2b(v2), h3 = f2b(v3);
            size_t o = afrag_idx(nn, k0 + k4) >> 2;     // same formula, n plays "row"
            ((unsigned long long*)Wh)[o] = pack4(h0, h1, h2, h3);
            ((unsigned long long*)Wl)[o] = pack4(f2b(v0 - b2f(h0)), f2b(v1 - b2f(h1)),
                                                 f2b(v2 - b2f(h2)), f2b(v3 - b2f(h3)));
        }
        return;
    }
    // ---- gstart ----
    if (t <= NG) {
        int lo = 0, hi = pa.n;
        while (lo < hi) {
            int mid = (lo + hi) >> 1;
            if (pa.batch[mid] < t) lo = mid + 1; else hi = mid;
        }
        pa.gstart[t] = lo;
    }
}

// ---------------------------------------------------------------------------
// K2: six split-bf16 MFMA projections (z<6, frag-order operands, head-major out)
//     + edge-bias scatter into packed-bf16 Bias (z==6, CAS add of both halves).
// Q/TQ (Clo != null): full 3-pass split. K/V/TK/TV: 2-pass (drop al*bh).
struct GB {
    const unsigned short* Ah[6];
    const unsigned short* Al[6];
    const float* bias[6];
    unsigned short* Chi[6];   // head-major [NH][M][HD]
    unsigned short* Clo[6];   // non-null -> also store residual lo
    float cscale[6];
};

__global__ __launch_bounds__(256) void k_gemm_split(GB gb,
        const unsigned short* __restrict__ whb, const unsigned short* __restrict__ wlb, int M,
        const int* __restrict__ ei, const float* __restrict__ eattr,
        const float* __restrict__ We, const float* __restrict__ be,
        const int* __restrict__ batch, const int* __restrict__ gstart,
        unsigned int* __restrict__ BiasP, int E) {
    const int z = blockIdx.z;
    const int t = threadIdx.x;

    if (z == 6) {            // ---- edge bias scatter into packed bf16 Bias ----
        const int stride = gridDim.x * gridDim.y * 256;
        for (int e = (blockIdx.y * gridDim.x + blockIdx.x) * 256 + t; e < E; e += stride) {
            int src = ei[e], dst = ei[E + e];
            if (src < 0 || src >= M || dst < 0 || dst >= M) continue;
            int bs = batch[src];
            if (bs != batch[dst]) continue;
            float4 a = *(const float4*)(eattr + (size_t)e * 4);
            int col = dst - gstart[bs];
            float vh[NH];
#pragma unroll
            for (int h = 0; h < NH; h++) {
                vh[h] = a.x * We[0 * NH + h] + a.y * We[1 * NH + h] +
                        a.z * We[2 * NH + h] + a.w * We[3 * NH + h] + be[h];
            }
#pragma unroll
            for (int hp = 0; hp < 4; hp++) {
                unsigned int* addr = BiasP + ((size_t)hp * M + src) * LB + col;
                float v0 = vh[2 * hp], v1 = vh[2 * hp + 1];
                unsigned int old = *addr, assumed;
                do {
                    assumed = old;
                    float lo = b2f((unsigned short)(assumed & 0xFFFFu)) + v0;
                    float hi = b2f((unsigned short)(assumed >> 16)) + v1;
                    unsigned int nw = (unsigned)f2b(lo) | ((unsigned)f2b(hi) << 16);
                    old = atomicCAS(addr, assumed, nw);
                } while (old != assumed);
            }
        }
        return;
    }

    const unsigned short* Ah = gb.Ah[z];
    const unsigned short* Al = gb.Al[z];
    const unsigned short* Wh = whb + (size_t)z * 65536;
    const unsigned short* Wl = wlb + (size_t)z * 65536;
    const float* bias = gb.bias[z];
    unsigned short* Chi = gb.Chi[z];
    unsigned short* Clo = gb.Clo[z];
    const float cs = gb.cscale[z];
    const bool fs = (Clo != nullptr);         // full-split arithmetic for Q/TQ only

    const int lane = t & 63, wv = t >> 6, lr = lane & 15, lq = lane >> 4;
    const int bm = blockIdx.x * 64 + (wv >> 1) * 32;
    const int bn = blockIdx.y * 64 + (wv & 1) * 32;
    const int mg0 = bm >> 4, ng0 = bn >> 4;     // fragment group bases (M%64==0)

    f32x4 acc[2][2] = {};
#pragma unroll
    for (int kc = 0; kc < 8; kc++) {
        s16x8 ah[2], al[2], bh[2], bl[2];
#pragma unroll
        for (int mi = 0; mi < 2; mi++) {
            size_t o = ((size_t)((mg0 + mi) * 8 + kc) << 9) + lane * 8;   // contiguous 1KB/wave
            ah[mi] = *(const s16x8*)(Ah + o);
            if (fs) al[mi] = *(const s16x8*)(Al + o);
        }
#pragma unroll
        for (int ni = 0; ni < 2; ni++) {
            size_t o = ((size_t)((ng0 + ni) * 8 + kc) << 9) + lane * 8;
            bh[ni] = *(const s16x8*)(Wh + o);
            bl[ni] = *(const s16x8*)(Wl + o);
        }
#pragma unroll
        for (int mi = 0; mi < 2; mi++)
#pragma unroll
            for (int ni = 0; ni < 2; ni++) {
                if (fs)
                    acc[mi][ni] = __builtin_amdgcn_mfma_f32_16x16x32_bf16(al[mi], bh[ni], acc[mi][ni], 0, 0, 0);
                acc[mi][ni] = __builtin_amdgcn_mfma_f32_16x16x32_bf16(ah[mi], bl[ni], acc[mi][ni], 0, 0, 0);
                acc[mi][ni] = __builtin_amdgcn_mfma_f32_16x16x32_bf16(ah[mi], bh[ni], acc[mi][ni], 0, 0, 0);
            }
    }
#pragma unroll
    for (int ni = 0; ni < 2; ni++) {
        const int col = bn + ni * 16 + lr;        // bn%32==0 -> head uniform per ni
        const int hh = col >> 5, dd = col & 31;
        float bv = bias[col];
#pragma unroll
        for (int mi = 0; mi < 2; mi++) {
#pragma unroll
            for (int r = 0; r < 4; r++) {
                int crow = bm + mi * 16 + 4 * lq + r;
                if (crow < M) {
                    float val = (acc[mi][ni][r] + bv) * cs;
                    unsigned short h = f2b(val);
                    size_t o = ((size_t)hh * M + crow) * HD + dd;
                    Chi[o] = h;
                    if (fs) Clo[o] = f2b(val - b2f(h));
                }
            }
        }
    }
}

// ---------------------------------------------------------------------------
// K3: flash MFMA attention, tz-merged (r13 structure, proven 56.9us). Block =
// 4 waves (256), 64 q-rows of (g, h). Bias read from packed-bf16 (2 heads/u32).
// Epilogue writes combined output as split-bf16 in A-frag order (ch, cl).
__global__ __launch_bounds__(256) void k_attn5(
    const unsigned short* __restrict__ Qh, const unsigned short* __restrict__ Ql,
    const unsigned short* __restrict__ K, const unsigned short* __restrict__ V,
    const unsigned short* __restrict__ TQh, const unsigned short* __restrict__ TQl,
    const unsigned short* __restrict__ TK, const unsigned short* __restrict__ TV,
    const int* __restrict__ gstart, const unsigned int* __restrict__ BiasP,
    unsigned short* __restrict__ ch, unsigned short* __restrict__ cl, int n) {

    const int g  = blockIdx.x / TPB;
    const int tp = blockIdx.x % TPB;
    const int h  = blockIdx.y;
    const int gs = gstart[g], ge = gstart[g + 1];
    const int L  = ge - gs;
    const int q0b = tp * 64;
    if (q0b >= L) return;                    // uniform block-level exit (before barriers)
    const int NC = (L + 31) >> 5;            // 32-key chunks

    __shared__ __align__(16) unsigned int Vt[32 * VRU];          // 25.6 KB: V^T [d][key-pair]
    __shared__ __align__(16) unsigned short Pb[4][16][40];       // 5 KB: per-wave P bounce

    const int t = threadIdx.x;
    const int wv = t >> 6, lane = t & 63;
    const int lr = lane & 15, lq = lane >> 4;
    const size_t hb = (size_t)h * n;          // head-major base row
    const int hsh = (h & 1) * 16;             // packed-bias half shift

    const int q0w = q0b + wv * 16;            // this wave's 16 rows (predicated)
    int gq = gs + q0w + lr;
    if (gq > ge - 1) gq = ge - 1;

    float os0[4] = {0.f, 0.f, 0.f, 0.f};      // accumulated normalized out (dims lr, 16+lr)
    float os1[4] = {0.f, 0.f, 0.f, 0.f};

    for (int tz = 0; tz < 2; tz++) {
        const unsigned short* Qph = tz ? TQh : Qh;
        const unsigned short* Qpl = tz ? TQl : Ql;
        const unsigned short* Kp  = tz ? TK  : K;
        const unsigned short* Vp  = tz ? TV  : V;
        const bool hasb = (tz == 0);

        if (tz) __syncthreads();              // all PV reads of prev Vt done

        // ---- cooperative V^T staging (all 4 waves), zero-padded keys ----
        {
            const int d0 = (t & 7) * 4;
            for (int jp = t >> 3; jp < NC * 16; jp += 32) {
                int j0 = jp * 2;
                unsigned short a0 = 0, a1 = 0, a2 = 0, a3 = 0, b0 = 0, b1 = 0, b2 = 0, b3 = 0;
                if (j0 < L) {
                    const unsigned short* vp = Vp + (hb + gs + j0) * HD + d0;
                    a0 = vp[0]; a1 = vp[1]; a2 = vp[2]; a3 = vp[3];
                }
                if (j0 + 1 < L) {
                    const unsigned short* vp = Vp + (hb + gs + j0 + 1) * HD + d0;
                    b0 = vp[0]; b1 = vp[1]; b2 = vp[2]; b3 = vp[3];
                }
                Vt[(d0 + 0) * VRU + jp] = (unsigned)a0 | ((unsigned)b0 << 16);
                Vt[(d0 + 1) * VRU + jp] = (unsigned)a1 | ((unsigned)b1 << 16);
                Vt[(d0 + 2) * VRU + jp] = (unsigned)a2 | ((unsigned)b2 << 16);
                Vt[(d0 + 3) * VRU + jp] = (unsigned)a3 | ((unsigned)b3 << 16);
            }
        }

        // ---- Q fragments: row = lr, k = 8*lq..+7 (clamped address, predicated use) ----
        s16x8 qfh = *(const s16x8*)(Qph + (hb + gq) * HD + lq * 8);
        s16x8 qfl = *(const s16x8*)(Qpl + (hb + gq) * HD + lq * 8);
        __syncthreads();                      // Vt ready

        // ---- per-reg packed-bias row bases (query rows 4*lq + r), spatial only ----
        const unsigned int* bw0 = BiasP; const unsigned int* bw1 = BiasP;
        const unsigned int* bw2 = BiasP; const unsigned int* bw3 = BiasP;
        if (hasb) {
            const size_t pb = (size_t)(h >> 1) * n;
            int r0 = gs + q0w + 4 * lq;
            int a0 = r0 + 0 < n ? r0 + 0 : n - 1;
            int a1 = r0 + 1 < n ? r0 + 1 : n - 1;
            int a2 = r0 + 2 < n ? r0 + 2 : n - 1;
            int a3 = r0 + 3 < n ? r0 + 3 : n - 1;
            bw0 = BiasP + (pb + a0) * LB;
            bw1 = BiasP + (pb + a1) * LB;
            bw2 = BiasP + (pb + a2) * LB;
            bw3 = BiasP + (pb + a3) * LB;
        }

        auto loadK = [&](int c, int half) -> s16x8 {
            int key = (2 * c + half) * 16 + lr;
            int krow = (key < L) ? (gs + key) : (ge - 1);
            return *(const s16x8*)(Kp + (hb + krow) * HD + lq * 8);
        };

        f32x4 acc0 = {0.f, 0.f, 0.f, 0.f};
        f32x4 acc1 = {0.f, 0.f, 0.f, 0.f};
        float ps0 = 0.f, ps1 = 0.f, ps2 = 0.f, ps3 = 0.f;

        s16x8 kfa = loadK(0, 0), kfb = loadK(0, 1);   // 1-deep prefetch
        for (int c = 0; c < NC; c++) {
            const int cn = (c + 1 < NC) ? c + 1 : c;
            s16x8 nka = loadK(cn, 0), nkb = loadK(cn, 1);

            float p[2][4];
#pragma unroll
            for (int half = 0; half < 2; half++) {
                const int key = (2 * c + half) * 16 + lr;
                s16x8 kf = half ? kfb : kfa;
                f32x4 d = {0.f, 0.f, 0.f, 0.f};
                d = __builtin_amdgcn_mfma_f32_16x16x32_bf16(qfl, kf, d, 0, 0, 0);
                d = __builtin_amdgcn_mfma_f32_16x16x32_bf16(qfh, kf, d, 0, 0, 0);
                float s0 = d[0], s1 = d[1], s2 = d[2], s3 = d[3];
                if (hasb) {
                    s0 += b2f((unsigned short)((bw0[key] >> hsh) & 0xFFFFu));
                    s1 += b2f((unsigned short)((bw1[key] >> hsh) & 0xFFFFu));
                    s2 += b2f((unsigned short)((bw2[key] >> hsh) & 0xFFFFu));
                    s3 += b2f((unsigned short)((bw3[key] >> hsh) & 0xFFFFu));
                }
                const bool ok = key < L;
                s0 = ok ? s0 : -3.0e38f;
                s1 = ok ? s1 : -3.0e38f;
                s2 = ok ? s2 : -3.0e38f;
                s3 = ok ? s3 : -3.0e38f;
                p[half][0] = __expf(s0 - FM);
                p[half][1] = __expf(s1 - FM);
                p[half][2] = __expf(s2 - FM);
                p[half][3] = __expf(s3 - FM);
            }
            ps0 += p[0][0] + p[1][0];
            ps1 += p[0][1] + p[1][1];
            ps2 += p[0][2] + p[1][2];
            ps3 += p[0][3] + p[1][3];
            // transpose bounce: D-layout (row 4lq+r, col lr) -> A-layout (row lr, k 8lq+j)
#pragma unroll
            for (int half = 0; half < 2; half++) {
#pragma unroll
                for (int r = 0; r < 4; r++)
                    Pb[wv][4 * lq + r][half * 16 + lr] = f2b(p[half][r]);
            }
            s16x8 pf  = *(const s16x8*)&Pb[wv][lr][8 * lq];
            s16x8 vf0 = *(const s16x8*)&Vt[(size_t)lr * VRU + c * 16 + lq * 4];
            s16x8 vf1 = *(const s16x8*)&Vt[(size_t)(16 + lr) * VRU + c * 16 + lq * 4];
            acc0 = __builtin_amdgcn_mfma_f32_16x16x32_bf16(pf, vf0, acc0, 0, 0, 0);
            acc1 = __builtin_amdgcn_mfma_f32_16x16x32_bf16(pf, vf1, acc1, 0, 0, 0);
            kfa = nka; kfb = nkb;
        }

        // ---- row-sums over the 16 lr lanes, normalize, accumulate ----
#pragma unroll
        for (int m = 1; m < 16; m <<= 1) {
            ps0 += __shfl_xor(ps0, m, 16);
            ps1 += __shfl_xor(ps1, m, 16);
            ps2 += __shfl_xor(ps2, m, 16);
            ps3 += __shfl_xor(ps3, m, 16);
        }
        float iv0 = 1.0f / ps0, iv1 = 1.0f / ps1, iv2 = 1.0f / ps2, iv3 = 1.0f / ps3;
        os0[0] += acc0[0] * iv0; os1[0] += acc1[0] * iv0;
        os0[1] += acc0[1] * iv1; os1[1] += acc1[1] * iv1;
        os0[2] += acc0[2] * iv2; os1[2] += acc1[2] * iv2;
        os0[3] += acc0[3] * iv3; os1[3] += acc1[3] * iv3;
    }

    // ---- store combined as split-bf16 in A-frag order (k = h*32 + d) ----
    const int qb = q0w + 4 * lq;
#pragma unroll
    for (int r = 0; r < 4; r++) {
        if (qb + r < L) {
            const int grow = gs + qb + r;
            float v0 = os0[r], v1 = os1[r];
            unsigned short h0 = f2b(v0);
            unsigned short l0 = f2b(v0 - b2f(h0));
            unsigned short h1 = f2b(v1);
            unsigned short l1 = f2b(v1 - b2f(h1));
            size_t o0 = afrag_idx(grow, h * HD + lr);
            size_t o1 = afrag_idx(grow, h * HD + 16 + lr);
            ch[o0] = h0; cl[o0] = l0;
            ch[o1] = h1; cl[o1] = l1;
        }
    }
}

// ---------------------------------------------------------------------------
// K4: split-bf16 MFMA output GEMM, frag-order A (from K3) and B (Wo).
// One wave per 16x32 C-tile: grid (M/16, 256/32) = 1024 blocks of 64 threads.
__global__ __launch_bounds__(64) void k_gemm_out(const unsigned short* __restrict__ Ah,
        const unsigned short* __restrict__ Al,
        const unsigned short* __restrict__ Wh, const unsigned short* __restrict__ Wl,
        const float* __restrict__ bias, float* __restrict__ C, int M) {
    const int lane = threadIdx.x;
    const int lr = lane & 15, lq = lane >> 4;
    const int bm = blockIdx.x * 16;
    const int bn = blockIdx.y * 32;
    const int mg = bm >> 4, ng0 = bn >> 4;

    f32x4 acc[2] = {};
#pragma unroll
    for (int kc = 0; kc < 8; kc++) {
        size_t oa = ((size_t)(mg * 8 + kc) << 9) + lane * 8;   // contiguous 1KB/wave
        s16x8 ah = *(const s16x8*)(Ah + oa);
        s16x8 al = *(const s16x8*)(Al + oa);
#pragma unroll
        for (int ni = 0; ni < 2; ni++) {
            size_t ob = ((size_t)((ng0 + ni) * 8 + kc) << 9) + lane * 8;
            s16x8 bh = *(const s16x8*)(Wh + ob);
            s16x8 bl = *(const s16x8*)(Wl + ob);
            acc[ni] = __builtin_amdgcn_mfma_f32_16x16x32_bf16(al, bh, acc[ni], 0, 0, 0);
            acc[ni] = __builtin_amdgcn_mfma_f32_16x16x32_bf16(ah, bl, acc[ni], 0, 0, 0);
            acc[ni] = __builtin_amdgcn_mfma_f32_16x16x32_bf16(ah, bh, acc[ni], 0, 0, 0);
        }
    }
#pragma unroll
    for (int ni = 0; ni < 2; ni++) {
        const int col = bn + ni * 16 + lr;
        float bv = bias[col];
#pragma unroll
        for (int r = 0; r < 4; r++) {
            const int crow = bm + 4 * lq + r;          // M%16==0 -> always in range
            C[(size_t)crow * 256 + col] = acc[ni][r] + bv;
        }
    }
}

// ---------------------------------------------------------------------------
extern "C" void kernel_launch(void* const* d_in, const int* in_sizes, int n_in,
                              void* d_out, int out_size, void* d_ws, size_t ws_size,
                              hipStream_t stream) {
    const float* x     = (const float*)d_in[0];
    const int*   ei    = (const int*)d_in[1];
    const float* eattr = (const float*)d_in[2];
    const int*   batch = (const int*)d_in[3];
    const int*   ti    = (const int*)d_in[4];
    const float* temb  = (const float*)d_in[5];
    const float* Wq = (const float*)d_in[6],  *bq = (const float*)d_in[7];
    const float* Wk = (const float*)d_in[8],  *bk = (const float*)d_in[9];
    const float* Wv = (const float*)d_in[10], *bv = (const float*)d_in[11];
    const float* Wo = (const float*)d_in[12], *bo = (const float*)d_in[13];
    const float* We = (const float*)d_in[14], *be = (const float*)d_in[15];
    const float* Wtq = (const float*)d_in[16], *btq = (const float*)d_in[17];
    const float* Wtk = (const float*)d_in[18], *btk = (const float*)d_in[19];
    const float* Wtv = (const float*)d_in[20], *btv = (const float*)d_in[21];

    const int n = in_sizes[0] / EMB;
    const int E = in_sizes[2] / 4;
    float* out = (float*)d_out;

    char* w = (char*)d_ws;
    auto alloc = [&](size_t bytes) -> void* {
        void* p = (void*)w;
        w += (bytes + 255) & ~(size_t)255;
        return p;
    };
    const size_t nb = (size_t)n * EMB * 2;   // one bf16 [n][256]-sized buffer
    unsigned short* xh   = (unsigned short*)alloc(nb);
    unsigned short* xl   = (unsigned short*)alloc(nb);
    unsigned short* eh   = (unsigned short*)alloc(nb);
    unsigned short* el   = (unsigned short*)alloc(nb);
    unsigned short* whb  = (unsigned short*)alloc((size_t)7 * 65536 * 2);
    unsigned short* wlb  = (unsigned short*)alloc((size_t)7 * 65536 * 2);
    unsigned short* Qhb  = (unsigned short*)alloc(nb);
    unsigned short* Qlb  = (unsigned short*)alloc(nb);
    unsigned short* Kb   = (unsigned short*)alloc(nb);
    unsigned short* Vb   = (unsigned short*)alloc(nb);
    unsigned short* TQhb = (unsigned short*)alloc(nb);
    unsigned short* TQlb = (unsigned short*)alloc(nb);
    unsigned short* TKb  = (unsigned short*)alloc(nb);
    unsigned short* TVb  = (unsigned short*)alloc(nb);
    unsigned int* BiasP  = (unsigned int*)alloc((size_t)(NH / 2) * n * LB * 4);  // 12.6 MB packed
    unsigned short* ch = (unsigned short*)alloc(nb);            // combined, frag order
    unsigned short* cl = (unsigned short*)alloc(nb);
    int* gstart  = (int*)alloc((NG + 1) * 4);

    // ---- K1: fused prep ----
    PrepArgs pa;
    pa.Bias4 = (u32x4*)BiasP;
    pa.bias4 = (NH / 2) * n * LB / 4;
    pa.x = x; pa.xh = xh; pa.xl = xl;
    pa.temb = temb; pa.ti = ti; pa.eh = eh; pa.el = el;
    pa.W[0] = Wq; pa.W[1] = Wk; pa.W[2] = Wv;
    pa.W[3] = Wtq; pa.W[4] = Wtk; pa.W[5] = Wtv; pa.W[6] = Wo;
    pa.whb = whb; pa.wlb = wlb;
    pa.batch = batch; pa.gstart = gstart; pa.n = n;
    pa.zb = (pa.bias4 + 255) / 256;
    pa.cvtb = (n * (EMB / 4) + 255) / 256;
    const int prep_blocks = pa.zb + 2 * pa.cvtb + 448 + 1;
    k_prep<<<dim3(prep_blocks), dim3(256), 0, stream>>>(pa);

    // ---- K2: projections (z<6, head-major out) + edge-bias scatter (z==6) ----
    const float scale = 0.17677669529663687f;
    GB gb;
    gb.Ah[0] = xh; gb.Al[0] = xl; gb.bias[0] = bq;  gb.Chi[0] = Qhb;  gb.Clo[0] = Qlb;  gb.cscale[0] = scale;
    gb.Ah[1] = xh; gb.Al[1] = xl; gb.bias[1] = bk;  gb.Chi[1] = Kb;   gb.Clo[1] = nullptr; gb.cscale[1] = 1.f;
    gb.Ah[2] = xh; gb.Al[2] = xl; gb.bias[2] = bv;  gb.Chi[2] = Vb;   gb.Clo[2] = nullptr; gb.cscale[2] = 1.f;
    gb.Ah[3] = eh; gb.Al[3] = el; gb.bias[3] = btq; gb.Chi[3] = TQhb; gb.Clo[3] = TQlb; gb.cscale[3] = scale;
    gb.Ah[4] = eh; gb.Al[4] = el; gb.bias[4] = btk; gb.Chi[4] = TKb;  gb.Clo[4] = nullptr; gb.cscale[4] = 1.f;
    gb.Ah[5] = eh; gb.Al[5] = el; gb.bias[5] = btv; gb.Chi[5] = TVb;  gb.Clo[5] = nullptr; gb.cscale[5] = 1.f;
    k_gemm_split<<<dim3((n + 63) / 64, EMB / 64, 7), dim3(256), 0, stream>>>(
        gb, whb, wlb, n, ei, eattr, We, be, batch, gstart, BiasP, E);

    // ---- K3: tz-merged flash MFMA attention -> combined (frag-order hi/lo) ----
    k_attn5<<<dim3(NG * TPB, NH), dim3(256), 0, stream>>>(Qhb, Qlb, Kb, Vb,
                                                          TQhb, TQlb, TKb, TVb,
                                                          gstart, BiasP, ch, cl, n);
    // ---- K4: output projection (1024 one-wave blocks) ----
    k_gemm_out<<<dim3(n / 16, EMB / 32), dim3(64), 0, stream>>>(
        ch, cl, whb + (size_t)6 * 65536, wlb + (size_t)6 * 65536, bo, out, n);
}